// Round 5
// baseline (2801.518 us; speedup 1.0000x reference)
//
#include <hip/hip_runtime.h>
#include <math.h>

// FNO1d: B=64, N=8192, F_IN=2, W=64, L=5, M=16, PAD=9 -> NLEN=8201
#define SROW 8208      // row stride (16-float aligned), >= NLEN
#define NLEN 8201
#define NB 64
#define W 64
#define M 16
#define NL 5
#define TWO_PI 6.283185307179586476925286766559

__device__ __forceinline__ float gelu_exact(float x) {
    return 0.5f * x * (1.0f + erff(x * 0.70710678118654752f));
}

// async global->LDS, 16B per lane: LDS dest = wave-uniform base + lane*16.
__device__ __forceinline__ void gld16(const float* g, float* l) {
    __builtin_amdgcn_global_load_lds(
        (const __attribute__((address_space(1))) void*)g,
        (__attribute__((address_space(3))) void*)l, 16, 0, 0);
}

// Build twiddle tables cosT[k][n], sinT[k][n] = cos/sin(2*pi*k*n/NLEN), fp64-accurate.
__global__ void ktable(float* __restrict__ cosT, float* __restrict__ sinT) {
    int n = blockIdx.x * 256 + threadIdx.x;
    int k = blockIdx.y;
    if (n >= SROW) return;
    long long m = ((long long)k * (long long)n) % NLEN;
    double th = (TWO_PI / (double)NLEN) * (double)m;
    double sv, cv;
    sincos(th, &sv, &cv);
    cosT[k * SROW + n] = (float)cv;
    sinT[k * SROW + n] = (float)sv;
}

// Lift: v[b][w][n] = x[b][n][:]@lift_w + lift_b  (n<8192), 0 in pad region.
__global__ __launch_bounds__(256) void klift(const float* __restrict__ x,
        const float* __restrict__ lw, const float* __restrict__ lb,
        float* __restrict__ v) {
    int n = blockIdx.x * 256 + threadIdx.x;
    int b = blockIdx.y;
    if (n >= SROW) return;
    bool in = (n < 8192);
    float x0 = 0.f, x1 = 0.f;
    if (in) {
        const float2 xx = *(const float2*)(x + ((size_t)b * 8192 + n) * 2);
        x0 = xx.x; x1 = xx.y;
    }
    float* vp = v + (size_t)b * W * SROW + n;
    #pragma unroll
    for (int w = 0; w < W; w++) {
        float val = in ? fmaf(x0, lw[w], fmaf(x1, lw[W + w], lb[w])) : 0.f;
        vp[(size_t)w * SROW] = val;
    }
}

// Forward DFT, 16 modes, float4-vectorized over n. Block: 4 rows; thread strides
// 4-wide chunks; k-recurrence from table row k=1. Tail n=8200 by thread 0.
__global__ __launch_bounds__(256) void kdft(const float* __restrict__ v,
        const float* __restrict__ cosT, const float* __restrict__ sinT,
        float* __restrict__ F) {
    int row0 = blockIdx.x * 4;
    int t = threadIdx.x;
    float accR[4][16], accI[4][16];
    #pragma unroll
    for (int r = 0; r < 4; r++)
        #pragma unroll
        for (int k = 0; k < 16; k++) { accR[r][k] = 0.f; accI[r][k] = 0.f; }
    const float* v0 = v + (size_t)row0 * SROW;
    for (int c = t; c < 2050; c += 256) {   // n = 4c .. 4c+3, covers n<8200
        int n = c << 2;
        float4 c1 = *(const float4*)(cosT + SROW + n);
        float4 s1 = *(const float4*)(sinT + SROW + n);
        float4 vv[4];
        #pragma unroll
        for (int r = 0; r < 4; r++) vv[r] = *(const float4*)(v0 + (size_t)r * SROW + n);
        #pragma unroll
        for (int r = 0; r < 4; r++)
            accR[r][0] += (vv[r].x + vv[r].y) + (vv[r].z + vv[r].w);
        float4 ck = c1, sk = s1;
        #pragma unroll
        for (int k = 1; k < 16; k++) {
            #pragma unroll
            for (int r = 0; r < 4; r++) {
                float ar = accR[r][k];
                ar = fmaf(vv[r].x, ck.x, ar); ar = fmaf(vv[r].y, ck.y, ar);
                ar = fmaf(vv[r].z, ck.z, ar); ar = fmaf(vv[r].w, ck.w, ar);
                accR[r][k] = ar;
                float ai = accI[r][k];
                ai = fmaf(-vv[r].x, sk.x, ai); ai = fmaf(-vv[r].y, sk.y, ai);
                ai = fmaf(-vv[r].z, sk.z, ai); ai = fmaf(-vv[r].w, sk.w, ai);
                accI[r][k] = ai;
            }
            if (k < 15) {
                float4 cn, sn;
                cn.x = fmaf(ck.x, c1.x, -sk.x * s1.x); sn.x = fmaf(ck.x, s1.x, sk.x * c1.x);
                cn.y = fmaf(ck.y, c1.y, -sk.y * s1.y); sn.y = fmaf(ck.y, s1.y, sk.y * c1.y);
                cn.z = fmaf(ck.z, c1.z, -sk.z * s1.z); sn.z = fmaf(ck.z, s1.z, sk.z * c1.z);
                cn.w = fmaf(ck.w, c1.w, -sk.w * s1.w); sn.w = fmaf(ck.w, s1.w, sk.w * c1.w);
                ck = cn; sk = sn;
            }
        }
    }
    if (t == 0) {        // tail n = 8200
        int n = 8200;
        #pragma unroll
        for (int k = 0; k < 16; k++) {
            float cv = cosT[k * SROW + n], sv = sinT[k * SROW + n];
            #pragma unroll
            for (int r = 0; r < 4; r++) {
                float vr = v0[(size_t)r * SROW + n];
                accR[r][k] = fmaf(vr, cv, accR[r][k]);
                accI[r][k] = fmaf(-vr, sv, accI[r][k]);
            }
        }
    }
    // wave butterfly reduce (64 lanes)
    #pragma unroll
    for (int r = 0; r < 4; r++)
        #pragma unroll
        for (int k = 0; k < 16; k++) {
            float xr = accR[r][k], xi = accI[r][k];
            #pragma unroll
            for (int off = 32; off > 0; off >>= 1) {
                xr += __shfl_down(xr, off, 64);
                xi += __shfl_down(xi, off, 64);
            }
            accR[r][k] = xr; accI[r][k] = xi;
        }
    __shared__ float red[4][128];
    int lane = t & 63, wv = t >> 6;
    if (lane == 0) {
        #pragma unroll
        for (int r = 0; r < 4; r++)
            #pragma unroll
            for (int k = 0; k < 16; k++) {
                red[wv][r * 32 + 2 * k]     = accR[r][k];
                red[wv][r * 32 + 2 * k + 1] = accI[r][k];
            }
    }
    __syncthreads();
    if (t < 128) {
        float sum = red[0][t] + red[1][t] + red[2][t] + red[3][t];
        int r = t >> 5, rem = t & 31, k = rem >> 1, comp = rem & 1;
        F[(((size_t)(row0 + r)) * M + k) * 2 + comp] = sum;
    }
}

// Mode mix: Pm[b][o][k] = sum_i F[b][i][k]*(kr+i*ki)[l][i][o][k], scaled 1/N | 2/N.
// Grid (64 b, 4 kg) x 256 threads: o = t&63, i-split 4 ways + LDS reduce.
// F loads are wave-uniform in o -> scalar path.
__global__ __launch_bounds__(256) void kmix(const float* __restrict__ F,
        const float* __restrict__ kr, const float* __restrict__ ki,
        float* __restrict__ Pm, int l) {
    int b = blockIdx.x, kg = blockIdx.y;
    int t = threadIdx.x;
    int o = t & 63, ii = t >> 6;   // 4 i-groups of 16
    const float* fb = F + (size_t)b * W * M * 2;
    const float* krl = kr + (size_t)l * W * W * M;
    const float* kil = ki + (size_t)l * W * W * M;
    float pr[4] = {0.f, 0.f, 0.f, 0.f}, pi[4] = {0.f, 0.f, 0.f, 0.f};
    for (int i = ii * 16; i < ii * 16 + 16; i++) {
        float4 kr4 = *(const float4*)(krl + ((size_t)i * W + o) * M + kg * 4);
        float4 ki4 = *(const float4*)(kil + ((size_t)i * W + o) * M + kg * 4);
        float4 f0 = *(const float4*)(fb + ((size_t)i * M + kg * 4) * 2);
        float4 f1 = *(const float4*)(fb + ((size_t)i * M + kg * 4) * 2 + 4);
        pr[0] += f0.x * kr4.x - f0.y * ki4.x;  pi[0] += f0.x * ki4.x + f0.y * kr4.x;
        pr[1] += f0.z * kr4.y - f0.w * ki4.y;  pi[1] += f0.z * ki4.y + f0.w * kr4.y;
        pr[2] += f1.x * kr4.z - f1.y * ki4.z;  pi[2] += f1.x * ki4.z + f1.y * kr4.z;
        pr[3] += f1.z * kr4.w - f1.w * ki4.w;  pi[3] += f1.z * ki4.w + f1.w * kr4.w;
    }
    __shared__ float red[4][64][8];
    #pragma unroll
    for (int c = 0; c < 4; c++) {
        red[ii][o][2 * c]     = pr[c];
        red[ii][o][2 * c + 1] = pi[c];
    }
    __syncthreads();
    if (ii == 0) {
        #pragma unroll
        for (int c = 0; c < 4; c++) {
            int k = kg * 4 + c;
            float sc = (k == 0) ? (1.0f / (float)NLEN) : (2.0f / (float)NLEN);
            float sr = red[0][o][2 * c] + red[1][o][2 * c] + red[2][o][2 * c] + red[3][o][2 * c];
            float si = red[0][o][2 * c + 1] + red[1][o][2 * c + 1] + red[2][o][2 * c + 1] + red[3][o][2 * c + 1];
            Pm[((size_t)b * W + o) * M * 2 + k * 2 + 0] = sr * sc;
            Pm[((size_t)b * W + o) * M * 2 + k * 2 + 1] = si * sc;
        }
    }
}

// Fused conv + inverse transform + gelu, IN-PLACE, LDS-staged double-buffered GEMM.
// Block: 64o x 128n of one b; thread: 8o x 4n. K padded to 96 (rows 94,95 zero-weight):
//   rows 0..63 = v, 64..78 = cos 1..15, 79..93 = sin 1..15.
// U chunks (12 rows x 128 n) staged async via global_load_lds, double-buffered.
// 4 blocks/CU (37.1 KB LDS, VGPR capped 128 by launch_bounds).
__global__ __launch_bounds__(256, 4) void kconv(float* v,
        const float* __restrict__ Pm, const float* __restrict__ cw,
        const float* __restrict__ cb, const float* __restrict__ cosT,
        const float* __restrict__ sinT, int l) {
    __shared__ __align__(16) float Wlds[96][64];       // 24 KB
    __shared__ __align__(16) float U[2][12][128];      // 12 KB
    __shared__ float bias[64];
    int t = threadIdx.x;
    int b = blockIdx.y;
    int n0 = blockIdx.x * 128;
    int lane = t & 63, wv = t >> 6;
    const float* cwl = cw + (size_t)l * W * W;
    const float* pmb = Pm + (size_t)b * W * M * 2;
    const float* vb = v + (size_t)b * W * SROW;

    // stage weights (96x64; rows 94,95 zero)
    #pragma unroll
    for (int it = 0; it < 24; it++) {
        int idx = t + it * 256;
        int k = idx >> 6, o = idx & 63;
        float w;
        if (k < 64)      w = cwl[o * 64 + k];
        else if (k < 79) w = pmb[o * 32 + (k - 63) * 2];        // +PmR mode 1..15
        else if (k < 94) w = -pmb[o * 32 + (k - 78) * 2 + 1];   // -PmI mode 1..15
        else             w = 0.f;
        Wlds[k][o] = w;
    }
    if (t < 64) bias[t] = cb[l * W + t] + pmb[t * 32];   // cb + PmR mode0 (scaled)

    // per-lane source column offset for staging
    int colf = n0 + (lane & 31) * 4;
    int rhalf = lane >> 5;

    // stage chunk 0
    #pragma unroll
    for (int p = 0; p < 6; p++) {
        if ((p & 3) == wv) {
            int row = 2 * p + rhalf;
            const float* src = (row < 64) ? vb + (size_t)row * SROW
                             : cosT + (size_t)(row - 63) * SROW;
            gld16(src + colf, &U[0][2 * p][0]);
        }
    }
    __syncthreads();

    int ln = t & 31;          // 32 n-groups of 4
    int og = t >> 5;          // 8 o-groups of 8
    int nn = n0 + ln * 4;
    float acc[8][4];
    #pragma unroll
    for (int r = 0; r < 8; r++) {
        float bs = bias[og * 8 + r];
        #pragma unroll
        for (int c = 0; c < 4; c++) acc[r][c] = bs;
    }

    int buf = 0;
    for (int c = 0; c < 8; c++) {
        if (c < 7) {   // prefetch next chunk into other buffer
            int k0 = (c + 1) * 12;
            #pragma unroll
            for (int p = 0; p < 6; p++) {
                if ((p & 3) == wv) {
                    int row = k0 + 2 * p + rhalf;
                    const float* src = (row < 64) ? vb + (size_t)row * SROW
                                     : (row < 79) ? cosT + (size_t)(row - 63) * SROW
                                     : (row < 94) ? sinT + (size_t)(row - 78) * SROW
                                     : sinT;   // rows 94,95: dummy (weights are 0)
                    gld16(src + colf, &U[buf ^ 1][2 * p][0]);
                }
            }
        }
        #pragma unroll
        for (int kk = 0; kk < 12; kk++) {
            int k = c * 12 + kk;
            float4 u = *(const float4*)&U[buf][kk][ln * 4];
            float4 wa = *(const float4*)&Wlds[k][og * 8];
            float4 wb = *(const float4*)&Wlds[k][og * 8 + 4];
            float wr[8] = {wa.x, wa.y, wa.z, wa.w, wb.x, wb.y, wb.z, wb.w};
            #pragma unroll
            for (int r = 0; r < 8; r++) {
                acc[r][0] = fmaf(wr[r], u.x, acc[r][0]);
                acc[r][1] = fmaf(wr[r], u.y, acc[r][1]);
                acc[r][2] = fmaf(wr[r], u.z, acc[r][2]);
                acc[r][3] = fmaf(wr[r], u.w, acc[r][3]);
            }
        }
        if (c < 7) { __syncthreads(); buf ^= 1; }
    }

    if (nn < SROW) {   // last block covers only 16 valid columns
        float* vo = v + (size_t)b * W * SROW + nn;
        #pragma unroll
        for (int r = 0; r < 8; r++) {
            float4 o4;
            o4.x = gelu_exact(acc[r][0]);
            o4.y = gelu_exact(acc[r][1]);
            o4.z = gelu_exact(acc[r][2]);
            o4.w = gelu_exact(acc[r][3]);
            *(float4*)(vo + (size_t)(og * 8 + r) * SROW) = o4;
        }
    }
}

// Final projection, LDS-staged: block = 128h x 128n of one b; thread 16h x 4n.
// K=64 in 8 chunks of 8, double-buffered via global_load_lds.
__global__ __launch_bounds__(256, 3) void kproj(const float* __restrict__ v,
        const float* __restrict__ w1, const float* __restrict__ b1,
        const float* __restrict__ w2, const float* __restrict__ b2,
        float* __restrict__ out) {
    __shared__ __align__(16) float W1[64][128];     // 32 KB, W1[k][h]
    __shared__ __align__(16) float U[2][8][128];    // 8 KB
    __shared__ float b1s[128], w2s[128];
    __shared__ __align__(16) float red[32][9][4];
    int t = threadIdx.x, b = blockIdx.y;
    int n0 = blockIdx.x * 128;
    int lane = t & 63, wv = t >> 6;
    const float* vb = v + (size_t)b * W * SROW;
    #pragma unroll
    for (int it = 0; it < 32; it++) ((float*)W1)[t + it * 256] = w1[t + it * 256];
    if (t < 128) { b1s[t] = b1[t]; w2s[t] = w2[t]; }

    int colf = n0 + (lane & 31) * 4;
    int rhalf = lane >> 5;
    if (wv < 4) {   // stage chunk 0: 4 row-pairs, one per wave
        int row = 2 * wv + rhalf;
        gld16(vb + (size_t)row * SROW + colf, &U[0][2 * wv][0]);
    }
    __syncthreads();

    int ln = t & 31, hg = t >> 5;
    float acc[16][4];
    #pragma unroll
    for (int r = 0; r < 16; r++) {
        float bs = b1s[hg * 16 + r];
        #pragma unroll
        for (int c = 0; c < 4; c++) acc[r][c] = bs;
    }

    int buf = 0;
    for (int c = 0; c < 8; c++) {
        if (c < 7) {
            int row = (c + 1) * 8 + 2 * wv + rhalf;
            gld16(vb + (size_t)row * SROW + colf, &U[buf ^ 1][2 * wv][0]);
        }
        #pragma unroll
        for (int kk = 0; kk < 8; kk++) {
            int k = c * 8 + kk;
            float4 u = *(const float4*)&U[buf][kk][ln * 4];
            #pragma unroll
            for (int q = 0; q < 4; q++) {
                float4 w4 = *(const float4*)&W1[k][hg * 16 + q * 4];
                float wr[4] = {w4.x, w4.y, w4.z, w4.w};
                #pragma unroll
                for (int rr = 0; rr < 4; rr++) {
                    int r = q * 4 + rr;
                    acc[r][0] = fmaf(wr[rr], u.x, acc[r][0]);
                    acc[r][1] = fmaf(wr[rr], u.y, acc[r][1]);
                    acc[r][2] = fmaf(wr[rr], u.z, acc[r][2]);
                    acc[r][3] = fmaf(wr[rr], u.w, acc[r][3]);
                }
            }
        }
        if (c < 7) { __syncthreads(); buf ^= 1; }
    }

    float p[4] = {0.f, 0.f, 0.f, 0.f};
    #pragma unroll
    for (int r = 0; r < 16; r++) {
        float wh = w2s[hg * 16 + r];
        #pragma unroll
        for (int c = 0; c < 4; c++) p[c] = fmaf(gelu_exact(acc[r][c]), wh, p[c]);
    }
    float4 p4 = {p[0], p[1], p[2], p[3]};
    *(float4*)&red[ln][hg][0] = p4;
    __syncthreads();
    if (t < 32) {
        float4 s = *(const float4*)&red[t][0][0];
        #pragma unroll
        for (int g = 1; g < 8; g++) {
            float4 q = *(const float4*)&red[t][g][0];
            s.x += q.x; s.y += q.y; s.z += q.z; s.w += q.w;
        }
        float bb = b2[0];
        s.x += bb; s.y += bb; s.z += bb; s.w += bb;
        *(float4*)(out + (size_t)b * 8192 + n0 + t * 4) = s;
    }
}

extern "C" void kernel_launch(void* const* d_in, const int* in_sizes, int n_in,
                              void* d_out, int out_size, void* d_ws, size_t ws_size,
                              hipStream_t stream) {
    const float* x  = (const float*)d_in[0];
    const float* lw = (const float*)d_in[1];
    const float* lb = (const float*)d_in[2];
    const float* kr = (const float*)d_in[3];
    const float* ki = (const float*)d_in[4];
    const float* cw = (const float*)d_in[5];
    const float* cb = (const float*)d_in[6];
    const float* w1 = (const float*)d_in[7];
    const float* b1 = (const float*)d_in[8];
    const float* w2 = (const float*)d_in[9];
    const float* b2 = (const float*)d_in[10];
    float* out = (float*)d_out;

    // workspace (floats): v 33,619,968 | cosT/sinT 131,328 ea | F/Pm 131,072 ea
    // total ~136.6 MB
    float* ws = (float*)d_ws;
    size_t vsz = (size_t)NB * W * SROW;
    float* v    = ws;
    float* cosT = v + vsz;
    float* sinT = cosT + (size_t)16 * SROW;
    float* F    = sinT + (size_t)16 * SROW;
    float* Pm   = F + (size_t)NB * W * M * 2;

    ktable<<<dim3(33, 16), 256, 0, stream>>>(cosT, sinT);
    klift<<<dim3(33, NB), 256, 0, stream>>>(x, lw, lb, v);

    for (int l = 0; l < NL; l++) {
        kdft<<<NB * W / 4, 256, 0, stream>>>(v, cosT, sinT, F);
        kmix<<<dim3(NB, 4), 256, 0, stream>>>(F, kr, ki, Pm, l);
        kconv<<<dim3(65, NB), 256, 0, stream>>>(v, Pm, cw, cb, cosT, sinT, l);
    }
    kproj<<<dim3(64, NB), 256, 0, stream>>>(v, w1, b1, w2, b2, out);
}

// Round 6
// 1737.595 us; speedup vs baseline: 1.6123x; 1.6123x over previous
//
#include <hip/hip_runtime.h>
#include <math.h>

// FNO1d: B=64, N=8192, F_IN=2, W=64, L=5, M=16, PAD=9 -> NLEN=8201
#define SROW 8208      // row stride (16-float aligned), >= NLEN
#define NLEN 8201
#define NB 64
#define W 64
#define M 16
#define NL 5
#define TWO_PI 6.283185307179586476925286766559

__device__ __forceinline__ float gelu_exact(float x) {
    return 0.5f * x * (1.0f + erff(x * 0.70710678118654752f));
}

// async global->LDS, 16B per lane: LDS dest = wave-uniform base + lane*16.
__device__ __forceinline__ void gld16(const float* g, float* l) {
    __builtin_amdgcn_global_load_lds(
        (const __attribute__((address_space(1))) void*)g,
        (__attribute__((address_space(3))) void*)l, 16, 0, 0);
}

// Twiddle tables cosT[k][n], sinT[k][n] (fp64-accurate) + ones/zeros rows.
__global__ void ktable(float* __restrict__ cosT, float* __restrict__ sinT,
                       float* __restrict__ onesz) {
    int n = blockIdx.x * 256 + threadIdx.x;
    int k = blockIdx.y;
    if (n >= SROW) return;
    if (k < 16) {
        long long m = ((long long)k * (long long)n) % NLEN;
        double th = (TWO_PI / (double)NLEN) * (double)m;
        double sv, cv;
        sincos(th, &sv, &cv);
        cosT[k * SROW + n] = (float)cv;
        sinT[k * SROW + n] = (float)sv;
    } else {
        onesz[(k - 16) * SROW + n] = (k == 16) ? 1.0f : 0.0f;
    }
}

// Lift: v[b][w][n] = x[b][n][:]@lift_w + lift_b  (n<8192), 0 in pad region.
__global__ __launch_bounds__(256) void klift(const float* __restrict__ x,
        const float* __restrict__ lw, const float* __restrict__ lb,
        float* __restrict__ v) {
    int n = blockIdx.x * 256 + threadIdx.x;
    int b = blockIdx.y;
    if (n >= SROW) return;
    bool in = (n < 8192);
    float x0 = 0.f, x1 = 0.f;
    if (in) {
        const float2 xx = *(const float2*)(x + ((size_t)b * 8192 + n) * 2);
        x0 = xx.x; x1 = xx.y;
    }
    float* vp = v + (size_t)b * W * SROW + n;
    #pragma unroll
    for (int w = 0; w < W; w++) {
        float val = in ? fmaf(x0, lw[w], fmaf(x1, lw[W + w], lb[w])) : 0.f;
        vp[(size_t)w * SROW] = val;
    }
}

// Forward DFT, 16 modes, float4-vectorized over n. Block: 4 rows.
__global__ __launch_bounds__(256) void kdft(const float* __restrict__ v,
        const float* __restrict__ cosT, const float* __restrict__ sinT,
        float* __restrict__ F) {
    int row0 = blockIdx.x * 4;
    int t = threadIdx.x;
    float accR[4][16], accI[4][16];
    #pragma unroll
    for (int r = 0; r < 4; r++)
        #pragma unroll
        for (int k = 0; k < 16; k++) { accR[r][k] = 0.f; accI[r][k] = 0.f; }
    const float* v0 = v + (size_t)row0 * SROW;
    for (int c = t; c < 2050; c += 256) {   // n = 4c .. 4c+3, covers n<8200
        int n = c << 2;
        float4 c1 = *(const float4*)(cosT + SROW + n);
        float4 s1 = *(const float4*)(sinT + SROW + n);
        float4 vv[4];
        #pragma unroll
        for (int r = 0; r < 4; r++) vv[r] = *(const float4*)(v0 + (size_t)r * SROW + n);
        #pragma unroll
        for (int r = 0; r < 4; r++)
            accR[r][0] += (vv[r].x + vv[r].y) + (vv[r].z + vv[r].w);
        float4 ck = c1, sk = s1;
        #pragma unroll
        for (int k = 1; k < 16; k++) {
            #pragma unroll
            for (int r = 0; r < 4; r++) {
                float ar = accR[r][k];
                ar = fmaf(vv[r].x, ck.x, ar); ar = fmaf(vv[r].y, ck.y, ar);
                ar = fmaf(vv[r].z, ck.z, ar); ar = fmaf(vv[r].w, ck.w, ar);
                accR[r][k] = ar;
                float ai = accI[r][k];
                ai = fmaf(-vv[r].x, sk.x, ai); ai = fmaf(-vv[r].y, sk.y, ai);
                ai = fmaf(-vv[r].z, sk.z, ai); ai = fmaf(-vv[r].w, sk.w, ai);
                accI[r][k] = ai;
            }
            if (k < 15) {
                float4 cn, sn;
                cn.x = fmaf(ck.x, c1.x, -sk.x * s1.x); sn.x = fmaf(ck.x, s1.x, sk.x * c1.x);
                cn.y = fmaf(ck.y, c1.y, -sk.y * s1.y); sn.y = fmaf(ck.y, s1.y, sk.y * c1.y);
                cn.z = fmaf(ck.z, c1.z, -sk.z * s1.z); sn.z = fmaf(ck.z, s1.z, sk.z * c1.z);
                cn.w = fmaf(ck.w, c1.w, -sk.w * s1.w); sn.w = fmaf(ck.w, s1.w, sk.w * c1.w);
                ck = cn; sk = sn;
            }
        }
    }
    if (t == 0) {        // tail n = 8200
        int n = 8200;
        #pragma unroll
        for (int k = 0; k < 16; k++) {
            float cv = cosT[k * SROW + n], sv = sinT[k * SROW + n];
            #pragma unroll
            for (int r = 0; r < 4; r++) {
                float vr = v0[(size_t)r * SROW + n];
                accR[r][k] = fmaf(vr, cv, accR[r][k]);
                accI[r][k] = fmaf(-vr, sv, accI[r][k]);
            }
        }
    }
    #pragma unroll
    for (int r = 0; r < 4; r++)
        #pragma unroll
        for (int k = 0; k < 16; k++) {
            float xr = accR[r][k], xi = accI[r][k];
            #pragma unroll
            for (int off = 32; off > 0; off >>= 1) {
                xr += __shfl_down(xr, off, 64);
                xi += __shfl_down(xi, off, 64);
            }
            accR[r][k] = xr; accI[r][k] = xi;
        }
    __shared__ float red[4][128];
    int lane = t & 63, wv = t >> 6;
    if (lane == 0) {
        #pragma unroll
        for (int r = 0; r < 4; r++)
            #pragma unroll
            for (int k = 0; k < 16; k++) {
                red[wv][r * 32 + 2 * k]     = accR[r][k];
                red[wv][r * 32 + 2 * k + 1] = accI[r][k];
            }
    }
    __syncthreads();
    if (t < 128) {
        float sum = red[0][t] + red[1][t] + red[2][t] + red[3][t];
        int r = t >> 5, rem = t & 31, k = rem >> 1, comp = rem & 1;
        F[(((size_t)(row0 + r)) * M + k) * 2 + comp] = sum;
    }
}

// Mode mix: Pm[b][o][k] = sum_i F[b][i][k]*(kr+i*ki)[l][i][o][k], scaled 1/N | 2/N.
__global__ __launch_bounds__(256) void kmix(const float* __restrict__ F,
        const float* __restrict__ kr, const float* __restrict__ ki,
        float* __restrict__ Pm, int l) {
    int b = blockIdx.x, kg = blockIdx.y;
    int t = threadIdx.x;
    int o = t & 63, ii = t >> 6;   // 4 i-groups of 16
    const float* fb = F + (size_t)b * W * M * 2;
    const float* krl = kr + (size_t)l * W * W * M;
    const float* kil = ki + (size_t)l * W * W * M;
    float pr[4] = {0.f, 0.f, 0.f, 0.f}, pi[4] = {0.f, 0.f, 0.f, 0.f};
    for (int i = ii * 16; i < ii * 16 + 16; i++) {
        float4 kr4 = *(const float4*)(krl + ((size_t)i * W + o) * M + kg * 4);
        float4 ki4 = *(const float4*)(kil + ((size_t)i * W + o) * M + kg * 4);
        float4 f0 = *(const float4*)(fb + ((size_t)i * M + kg * 4) * 2);
        float4 f1 = *(const float4*)(fb + ((size_t)i * M + kg * 4) * 2 + 4);
        pr[0] += f0.x * kr4.x - f0.y * ki4.x;  pi[0] += f0.x * ki4.x + f0.y * kr4.x;
        pr[1] += f0.z * kr4.y - f0.w * ki4.y;  pi[1] += f0.z * ki4.y + f0.w * kr4.y;
        pr[2] += f1.x * kr4.z - f1.y * ki4.z;  pi[2] += f1.x * ki4.z + f1.y * kr4.z;
        pr[3] += f1.z * kr4.w - f1.w * ki4.w;  pi[3] += f1.z * ki4.w + f1.w * kr4.w;
    }
    __shared__ float red[4][64][8];
    #pragma unroll
    for (int c = 0; c < 4; c++) {
        red[ii][o][2 * c]     = pr[c];
        red[ii][o][2 * c + 1] = pi[c];
    }
    __syncthreads();
    if (ii == 0) {
        #pragma unroll
        for (int c = 0; c < 4; c++) {
            int k = kg * 4 + c;
            float sc = (k == 0) ? (1.0f / (float)NLEN) : (2.0f / (float)NLEN);
            float sr = red[0][o][2 * c] + red[1][o][2 * c] + red[2][o][2 * c] + red[3][o][2 * c];
            float si = red[0][o][2 * c + 1] + red[1][o][2 * c + 1] + red[2][o][2 * c + 1] + red[3][o][2 * c + 1];
            Pm[((size_t)b * W + o) * M * 2 + k * 2 + 0] = sr * sc;
            Pm[((size_t)b * W + o) * M * 2 + k * 2 + 1] = si * sc;
        }
    }
}

// Build fused weight matrix Wf[b][96][64]:
//  k<64: cw[l][o][k]; 64..78: +PmR(1..15); 79..93: -PmI(1..15);
//  94: cb[o]+PmR(0) (u row 94 == 1); 95: 0 (u row 95 == 0).
__global__ __launch_bounds__(256) void kprep(const float* __restrict__ Pm,
        const float* __restrict__ cw, const float* __restrict__ cb,
        float* __restrict__ Wf, int l) {
    int b = blockIdx.x;
    int t = threadIdx.x;
    const float* cwl = cw + (size_t)l * W * W;
    const float* pmb = Pm + (size_t)b * W * M * 2;
    float* wb = Wf + (size_t)b * 96 * 64;
    #pragma unroll
    for (int it = 0; it < 24; it++) {
        int idx = t + it * 256;
        int k = idx >> 6, o = idx & 63;
        float w;
        if (k < 64)       w = cwl[o * 64 + k];
        else if (k < 79)  w = pmb[o * 32 + (k - 63) * 2];
        else if (k < 94)  w = -pmb[o * 32 + (k - 78) * 2 + 1];
        else if (k == 94) w = cb[l * W + o] + pmb[o * 32];
        else              w = 0.f;
        wb[idx] = w;
    }
}

// Fused conv + inverse transform + gelu, IN-PLACE. 512 threads = 8 waves.
// Wave w owns o rows [8w,8w+8); block covers 64o x 256n. Thread: 8o x 4n.
// Weights read wave-uniformly from global Wf -> s_load (scalar pipe).
// u (K=96 rows: v, cos, sin, ones, zeros) staged in LDS via global_load_lds,
// double-buffered 12-row chunks. Only LDS use is U (24 KB) -> high occupancy.
__global__ __launch_bounds__(512, 6) void kconv(float* v,
        const float* __restrict__ Wf, const float* __restrict__ cosT,
        const float* __restrict__ sinT, const float* __restrict__ onesz) {
    __shared__ __align__(16) float U[2][12][256];
    int t = threadIdx.x;
    int b = blockIdx.y;
    int n0 = blockIdx.x * 256;
    int lane = t & 63;
    int wvu = __builtin_amdgcn_readfirstlane(t >> 6);   // 0..7, provably uniform
    const float* vb = v + (size_t)b * (W * SROW);
    const float* Wb = Wf + (size_t)b * (96 * 64) + wvu * 8;
    int colf = n0 + lane * 4;

    // stage chunk 0 (rows 0..11, all v rows)
    gld16(vb + (size_t)wvu * SROW + colf, &U[0][wvu][0]);
    if (wvu < 4) gld16(vb + (size_t)(8 + wvu) * SROW + colf, &U[0][8 + wvu][0]);

    float acc[8][4];
    #pragma unroll
    for (int r = 0; r < 8; r++) { acc[r][0] = acc[r][1] = acc[r][2] = acc[r][3] = 0.f; }
    __syncthreads();

    int buf = 0;
    for (int c = 0; c < 8; c++) {
        if (c < 7) {
            int k0 = (c + 1) * 12;
            int r0 = k0 + wvu;
            const float* s0 = (r0 < 64) ? vb + (size_t)r0 * SROW
                            : (r0 < 79) ? cosT + (size_t)(r0 - 63) * SROW
                            : (r0 < 94) ? sinT + (size_t)(r0 - 78) * SROW
                            : onesz + (size_t)(r0 - 94) * SROW;
            gld16(s0 + colf, &U[buf ^ 1][wvu][0]);
            if (wvu < 4) {
                int r1 = k0 + 8 + wvu;
                const float* s1 = (r1 < 64) ? vb + (size_t)r1 * SROW
                                : (r1 < 79) ? cosT + (size_t)(r1 - 63) * SROW
                                : (r1 < 94) ? sinT + (size_t)(r1 - 78) * SROW
                                : onesz + (size_t)(r1 - 94) * SROW;
                gld16(s1 + colf, &U[buf ^ 1][8 + wvu][0]);
            }
        }
        #pragma unroll
        for (int kk = 0; kk < 12; kk++) {
            int k = c * 12 + kk;
            float4 u = *(const float4*)&U[buf][kk][lane * 4];
            const float* wk = Wb + k * 64;          // wave-uniform -> s_load
            #pragma unroll
            for (int r = 0; r < 8; r++) {
                float wr = wk[r];
                acc[r][0] = fmaf(wr, u.x, acc[r][0]);
                acc[r][1] = fmaf(wr, u.y, acc[r][1]);
                acc[r][2] = fmaf(wr, u.z, acc[r][2]);
                acc[r][3] = fmaf(wr, u.w, acc[r][3]);
            }
        }
        if (c < 7) { __syncthreads(); buf ^= 1; }
    }

    if (colf < SROW) {
        float* vo = v + (size_t)b * (W * SROW) + colf;
        #pragma unroll
        for (int r = 0; r < 8; r++) {
            float4 o4;
            o4.x = gelu_exact(acc[r][0]);
            o4.y = gelu_exact(acc[r][1]);
            o4.z = gelu_exact(acc[r][2]);
            o4.w = gelu_exact(acc[r][3]);
            *(float4*)(vo + (size_t)(wvu * 8 + r) * SROW) = o4;
        }
    }
}

// Final projection, same structure: 512 threads = 8 waves; wave w owns h rows
// [16w,16w+16); thread 16h x 4n; w1/b1/w2 read wave-uniformly (s_load).
// K=64 in 8 chunks of 8 rows, LDS double-buffered; LDS reduce over h-groups.
__global__ __launch_bounds__(512, 4) void kproj(const float* __restrict__ v,
        const float* __restrict__ w1, const float* __restrict__ b1,
        const float* __restrict__ w2, const float* __restrict__ b2,
        float* __restrict__ out) {
    __shared__ __align__(16) float U[2][8][256];
    __shared__ __align__(16) float red[8][256];
    int t = threadIdx.x;
    int b = blockIdx.y;
    int n0 = blockIdx.x * 256;   // 32 blocks x 256 = 8192 exact
    int lane = t & 63;
    int wvu = __builtin_amdgcn_readfirstlane(t >> 6);
    const float* vb = v + (size_t)b * (W * SROW);
    int colf = n0 + lane * 4;
    int h0 = wvu * 16;

    gld16(vb + (size_t)wvu * SROW + colf, &U[0][wvu][0]);

    float acc[16][4];
    #pragma unroll
    for (int r = 0; r < 16; r++) {
        float bs = b1[h0 + r];                      // uniform -> s_load
        acc[r][0] = acc[r][1] = acc[r][2] = acc[r][3] = bs;
    }
    __syncthreads();

    int buf = 0;
    for (int c = 0; c < 8; c++) {
        if (c < 7)
            gld16(vb + (size_t)((c + 1) * 8 + wvu) * SROW + colf, &U[buf ^ 1][wvu][0]);
        #pragma unroll
        for (int kk = 0; kk < 8; kk++) {
            int k = c * 8 + kk;
            float4 u = *(const float4*)&U[buf][kk][lane * 4];
            const float* wk = w1 + k * 128 + h0;    // uniform -> s_load
            #pragma unroll
            for (int r = 0; r < 16; r++) {
                float wr = wk[r];
                acc[r][0] = fmaf(wr, u.x, acc[r][0]);
                acc[r][1] = fmaf(wr, u.y, acc[r][1]);
                acc[r][2] = fmaf(wr, u.z, acc[r][2]);
                acc[r][3] = fmaf(wr, u.w, acc[r][3]);
            }
        }
        if (c < 7) { __syncthreads(); buf ^= 1; }
    }

    float p0 = 0.f, p1 = 0.f, p2 = 0.f, p3 = 0.f;
    #pragma unroll
    for (int r = 0; r < 16; r++) {
        float wh = w2[h0 + r];                      // uniform -> s_load
        p0 = fmaf(gelu_exact(acc[r][0]), wh, p0);
        p1 = fmaf(gelu_exact(acc[r][1]), wh, p1);
        p2 = fmaf(gelu_exact(acc[r][2]), wh, p2);
        p3 = fmaf(gelu_exact(acc[r][3]), wh, p3);
    }
    float4 p4 = {p0, p1, p2, p3};
    *(float4*)&red[wvu][lane * 4] = p4;
    __syncthreads();
    if (t < 256) {
        float s = b2[0];
        #pragma unroll
        for (int w = 0; w < 8; w++) s += red[w][t];
        out[(size_t)b * 8192 + n0 + t] = s;
    }
}

extern "C" void kernel_launch(void* const* d_in, const int* in_sizes, int n_in,
                              void* d_out, int out_size, void* d_ws, size_t ws_size,
                              hipStream_t stream) {
    const float* x  = (const float*)d_in[0];
    const float* lw = (const float*)d_in[1];
    const float* lb = (const float*)d_in[2];
    const float* kr = (const float*)d_in[3];
    const float* ki = (const float*)d_in[4];
    const float* cw = (const float*)d_in[5];
    const float* cb = (const float*)d_in[6];
    const float* w1 = (const float*)d_in[7];
    const float* b1 = (const float*)d_in[8];
    const float* w2 = (const float*)d_in[9];
    const float* b2 = (const float*)d_in[10];
    float* out = (float*)d_out;

    // workspace (floats): v 33,619,968 | cosT/sinT 131,328 ea | onesz 24,624 |
    // F/Pm 131,072 ea | Wf 393,216  => ~138.3 MB
    float* ws = (float*)d_ws;
    size_t vsz = (size_t)NB * W * SROW;
    float* v     = ws;
    float* cosT  = v + vsz;
    float* sinT  = cosT + (size_t)16 * SROW;
    float* onesz = sinT + (size_t)16 * SROW;
    float* F     = onesz + (size_t)3 * SROW;
    float* Pm    = F + (size_t)NB * W * M * 2;
    float* Wf    = Pm + (size_t)NB * W * M * 2;

    ktable<<<dim3(33, 18), 256, 0, stream>>>(cosT, sinT, onesz);
    klift<<<dim3(33, NB), 256, 0, stream>>>(x, lw, lb, v);

    for (int l = 0; l < NL; l++) {
        kdft<<<NB * W / 4, 256, 0, stream>>>(v, cosT, sinT, F);
        kmix<<<dim3(NB, 4), 256, 0, stream>>>(F, kr, ki, Pm, l);
        kprep<<<NB, 256, 0, stream>>>(Pm, cw, cb, Wf, l);
        kconv<<<dim3(33, NB), 512, 0, stream>>>(v, Wf, cosT, sinT, onesz);
    }
    kproj<<<dim3(32, NB), 512, 0, stream>>>(v, w1, b1, w2, b2, out);
}

// Round 7
// 1479.376 us; speedup vs baseline: 1.8937x; 1.1745x over previous
//
#include <hip/hip_runtime.h>
#include <math.h>

// FNO1d: B=64, N=8192, F_IN=2, W=64, L=5, M=16, PAD=9 -> NLEN=8201
#define SROW 8208      // row stride (16-float aligned), >= NLEN
#define NLEN 8201
#define NB 64
#define W 64
#define M 16
#define NL 5
#define TWO_PI 6.283185307179586476925286766559

__device__ __forceinline__ float gelu_exact(float x) {
    return 0.5f * x * (1.0f + erff(x * 0.70710678118654752f));
}

// async global->LDS, 16B per lane: LDS dest = wave-uniform base + lane*16.
__device__ __forceinline__ void gld16(const float* g, float* l) {
    __builtin_amdgcn_global_load_lds(
        (const __attribute__((address_space(1))) void*)g,
        (__attribute__((address_space(3))) void*)l, 16, 0, 0);
}

// Twiddle tables cosT[k][n], sinT[k][n] (fp64-accurate) + ones/zeros rows.
__global__ void ktable(float* __restrict__ cosT, float* __restrict__ sinT,
                       float* __restrict__ onesz) {
    int n = blockIdx.x * 256 + threadIdx.x;
    int k = blockIdx.y;
    if (n >= SROW) return;
    if (k < 16) {
        long long m = ((long long)k * (long long)n) % NLEN;
        double th = (TWO_PI / (double)NLEN) * (double)m;
        double sv, cv;
        sincos(th, &sv, &cv);
        cosT[k * SROW + n] = (float)cv;
        sinT[k * SROW + n] = (float)sv;
    } else {
        onesz[(k - 16) * SROW + n] = (k == 16) ? 1.0f : 0.0f;
    }
}

// Lift: v[b][w][n] = x[b][n][:]@lift_w + lift_b  (n<8192), 0 in pad region.
__global__ __launch_bounds__(256) void klift(const float* __restrict__ x,
        const float* __restrict__ lw, const float* __restrict__ lb,
        float* __restrict__ v) {
    int n = blockIdx.x * 256 + threadIdx.x;
    int b = blockIdx.y;
    if (n >= SROW) return;
    bool in = (n < 8192);
    float x0 = 0.f, x1 = 0.f;
    if (in) {
        const float2 xx = *(const float2*)(x + ((size_t)b * 8192 + n) * 2);
        x0 = xx.x; x1 = xx.y;
    }
    float* vp = v + (size_t)b * W * SROW + n;
    #pragma unroll
    for (int w = 0; w < W; w++) {
        float val = in ? fmaf(x0, lw[w], fmaf(x1, lw[W + w], lb[w])) : 0.f;
        vp[(size_t)w * SROW] = val;
    }
}

// Forward DFT, 16 modes, float4-vectorized over n. Block: 4 rows.
__global__ __launch_bounds__(256) void kdft(const float* __restrict__ v,
        const float* __restrict__ cosT, const float* __restrict__ sinT,
        float* __restrict__ F) {
    int row0 = blockIdx.x * 4;
    int t = threadIdx.x;
    float accR[4][16], accI[4][16];
    #pragma unroll
    for (int r = 0; r < 4; r++)
        #pragma unroll
        for (int k = 0; k < 16; k++) { accR[r][k] = 0.f; accI[r][k] = 0.f; }
    const float* v0 = v + (size_t)row0 * SROW;
    for (int c = t; c < 2050; c += 256) {   // n = 4c .. 4c+3, covers n<8200
        int n = c << 2;
        float4 c1 = *(const float4*)(cosT + SROW + n);
        float4 s1 = *(const float4*)(sinT + SROW + n);
        float4 vv[4];
        #pragma unroll
        for (int r = 0; r < 4; r++) vv[r] = *(const float4*)(v0 + (size_t)r * SROW + n);
        #pragma unroll
        for (int r = 0; r < 4; r++)
            accR[r][0] += (vv[r].x + vv[r].y) + (vv[r].z + vv[r].w);
        float4 ck = c1, sk = s1;
        #pragma unroll
        for (int k = 1; k < 16; k++) {
            #pragma unroll
            for (int r = 0; r < 4; r++) {
                float ar = accR[r][k];
                ar = fmaf(vv[r].x, ck.x, ar); ar = fmaf(vv[r].y, ck.y, ar);
                ar = fmaf(vv[r].z, ck.z, ar); ar = fmaf(vv[r].w, ck.w, ar);
                accR[r][k] = ar;
                float ai = accI[r][k];
                ai = fmaf(-vv[r].x, sk.x, ai); ai = fmaf(-vv[r].y, sk.y, ai);
                ai = fmaf(-vv[r].z, sk.z, ai); ai = fmaf(-vv[r].w, sk.w, ai);
                accI[r][k] = ai;
            }
            if (k < 15) {
                float4 cn, sn;
                cn.x = fmaf(ck.x, c1.x, -sk.x * s1.x); sn.x = fmaf(ck.x, s1.x, sk.x * c1.x);
                cn.y = fmaf(ck.y, c1.y, -sk.y * s1.y); sn.y = fmaf(ck.y, s1.y, sk.y * c1.y);
                cn.z = fmaf(ck.z, c1.z, -sk.z * s1.z); sn.z = fmaf(ck.z, s1.z, sk.z * c1.z);
                cn.w = fmaf(ck.w, c1.w, -sk.w * s1.w); sn.w = fmaf(ck.w, s1.w, sk.w * c1.w);
                ck = cn; sk = sn;
            }
        }
    }
    if (t == 0) {        // tail n = 8200
        int n = 8200;
        #pragma unroll
        for (int k = 0; k < 16; k++) {
            float cv = cosT[k * SROW + n], sv = sinT[k * SROW + n];
            #pragma unroll
            for (int r = 0; r < 4; r++) {
                float vr = v0[(size_t)r * SROW + n];
                accR[r][k] = fmaf(vr, cv, accR[r][k]);
                accI[r][k] = fmaf(-vr, sv, accI[r][k]);
            }
        }
    }
    #pragma unroll
    for (int r = 0; r < 4; r++)
        #pragma unroll
        for (int k = 0; k < 16; k++) {
            float xr = accR[r][k], xi = accI[r][k];
            #pragma unroll
            for (int off = 32; off > 0; off >>= 1) {
                xr += __shfl_down(xr, off, 64);
                xi += __shfl_down(xi, off, 64);
            }
            accR[r][k] = xr; accI[r][k] = xi;
        }
    __shared__ float red[4][128];
    int lane = t & 63, wv = t >> 6;
    if (lane == 0) {
        #pragma unroll
        for (int r = 0; r < 4; r++)
            #pragma unroll
            for (int k = 0; k < 16; k++) {
                red[wv][r * 32 + 2 * k]     = accR[r][k];
                red[wv][r * 32 + 2 * k + 1] = accI[r][k];
            }
    }
    __syncthreads();
    if (t < 128) {
        float sum = red[0][t] + red[1][t] + red[2][t] + red[3][t];
        int r = t >> 5, rem = t & 31, k = rem >> 1, comp = rem & 1;
        F[(((size_t)(row0 + r)) * M + k) * 2 + comp] = sum;
    }
}

// Mode mix: Pm[b][o][k] = sum_i F[b][i][k]*(kr+i*ki)[l][i][o][k], scaled 1/N | 2/N.
__global__ __launch_bounds__(256) void kmix(const float* __restrict__ F,
        const float* __restrict__ kr, const float* __restrict__ ki,
        float* __restrict__ Pm, int l) {
    int b = blockIdx.x, kg = blockIdx.y;
    int t = threadIdx.x;
    int o = t & 63, ii = t >> 6;   // 4 i-groups of 16
    const float* fb = F + (size_t)b * W * M * 2;
    const float* krl = kr + (size_t)l * W * W * M;
    const float* kil = ki + (size_t)l * W * W * M;
    float pr[4] = {0.f, 0.f, 0.f, 0.f}, pi[4] = {0.f, 0.f, 0.f, 0.f};
    for (int i = ii * 16; i < ii * 16 + 16; i++) {
        float4 kr4 = *(const float4*)(krl + ((size_t)i * W + o) * M + kg * 4);
        float4 ki4 = *(const float4*)(kil + ((size_t)i * W + o) * M + kg * 4);
        float4 f0 = *(const float4*)(fb + ((size_t)i * M + kg * 4) * 2);
        float4 f1 = *(const float4*)(fb + ((size_t)i * M + kg * 4) * 2 + 4);
        pr[0] += f0.x * kr4.x - f0.y * ki4.x;  pi[0] += f0.x * ki4.x + f0.y * kr4.x;
        pr[1] += f0.z * kr4.y - f0.w * ki4.y;  pi[1] += f0.z * ki4.y + f0.w * kr4.y;
        pr[2] += f1.x * kr4.z - f1.y * ki4.z;  pi[2] += f1.x * ki4.z + f1.y * kr4.z;
        pr[3] += f1.z * kr4.w - f1.w * ki4.w;  pi[3] += f1.z * ki4.w + f1.w * kr4.w;
    }
    __shared__ float red[4][64][8];
    #pragma unroll
    for (int c = 0; c < 4; c++) {
        red[ii][o][2 * c]     = pr[c];
        red[ii][o][2 * c + 1] = pi[c];
    }
    __syncthreads();
    if (ii == 0) {
        #pragma unroll
        for (int c = 0; c < 4; c++) {
            int k = kg * 4 + c;
            float sc = (k == 0) ? (1.0f / (float)NLEN) : (2.0f / (float)NLEN);
            float sr = red[0][o][2 * c] + red[1][o][2 * c] + red[2][o][2 * c] + red[3][o][2 * c];
            float si = red[0][o][2 * c + 1] + red[1][o][2 * c + 1] + red[2][o][2 * c + 1] + red[3][o][2 * c + 1];
            Pm[((size_t)b * W + o) * M * 2 + k * 2 + 0] = sr * sc;
            Pm[((size_t)b * W + o) * M * 2 + k * 2 + 1] = si * sc;
        }
    }
}

// Build fused weight matrix Wf[b][96][64]:
//  k<64: cw[l][o][k]; 64..78: +PmR(1..15); 79..93: -PmI(1..15);
//  94: cb[o]+PmR(0) (u row 94 == 1); 95: 0 (u row 95 == 0).
__global__ __launch_bounds__(256) void kprep(const float* __restrict__ Pm,
        const float* __restrict__ cw, const float* __restrict__ cb,
        float* __restrict__ Wf, int l) {
    int b = blockIdx.x;
    int t = threadIdx.x;
    const float* cwl = cw + (size_t)l * W * W;
    const float* pmb = Pm + (size_t)b * W * M * 2;
    float* wb = Wf + (size_t)b * 96 * 64;
    #pragma unroll
    for (int it = 0; it < 24; it++) {
        int idx = t + it * 256;
        int k = idx >> 6, o = idx & 63;
        float w;
        if (k < 64)       w = cwl[o * 64 + k];
        else if (k < 79)  w = pmb[o * 32 + (k - 63) * 2];
        else if (k < 94)  w = -pmb[o * 32 + (k - 78) * 2 + 1];
        else if (k == 94) w = cb[l * W + o] + pmb[o * 32];
        else              w = 0.f;
        wb[idx] = w;
    }
}

// Fused conv + inverse transform + gelu, IN-PLACE. 512 threads = 8 waves.
// Wave w owns o rows [8w,8w+8); block covers 64o x 256n. Thread: 8o x 4n.
// Weights read wave-uniformly from global Wf -> s_load (scalar pipe).
__global__ __launch_bounds__(512, 6) void kconv(float* v,
        const float* __restrict__ Wf, const float* __restrict__ cosT,
        const float* __restrict__ sinT, const float* __restrict__ onesz) {
    __shared__ __align__(16) float U[2][12][256];
    int t = threadIdx.x;
    int b = blockIdx.y;
    int n0 = blockIdx.x * 256;
    int lane = t & 63;
    int wvu = __builtin_amdgcn_readfirstlane(t >> 6);   // 0..7, provably uniform
    const float* vb = v + (size_t)b * (W * SROW);
    const float* Wb = Wf + (size_t)b * (96 * 64) + wvu * 8;
    int colf = n0 + lane * 4;

    // stage chunk 0 (rows 0..11, all v rows)
    gld16(vb + (size_t)wvu * SROW + colf, &U[0][wvu][0]);
    if (wvu < 4) gld16(vb + (size_t)(8 + wvu) * SROW + colf, &U[0][8 + wvu][0]);

    float acc[8][4];
    #pragma unroll
    for (int r = 0; r < 8; r++) { acc[r][0] = acc[r][1] = acc[r][2] = acc[r][3] = 0.f; }
    __syncthreads();

    int buf = 0;
    for (int c = 0; c < 8; c++) {
        if (c < 7) {
            int k0 = (c + 1) * 12;
            int r0 = k0 + wvu;
            const float* s0 = (r0 < 64) ? vb + (size_t)r0 * SROW
                            : (r0 < 79) ? cosT + (size_t)(r0 - 63) * SROW
                            : (r0 < 94) ? sinT + (size_t)(r0 - 78) * SROW
                            : onesz + (size_t)(r0 - 94) * SROW;
            gld16(s0 + colf, &U[buf ^ 1][wvu][0]);
            if (wvu < 4) {
                int r1 = k0 + 8 + wvu;
                const float* s1 = (r1 < 64) ? vb + (size_t)r1 * SROW
                                : (r1 < 79) ? cosT + (size_t)(r1 - 63) * SROW
                                : (r1 < 94) ? sinT + (size_t)(r1 - 78) * SROW
                                : onesz + (size_t)(r1 - 94) * SROW;
                gld16(s1 + colf, &U[buf ^ 1][8 + wvu][0]);
            }
        }
        #pragma unroll
        for (int kk = 0; kk < 12; kk++) {
            int k = c * 12 + kk;
            float4 u = *(const float4*)&U[buf][kk][lane * 4];
            const float* wk = Wb + k * 64;          // wave-uniform -> s_load
            #pragma unroll
            for (int r = 0; r < 8; r++) {
                float wr = wk[r];
                acc[r][0] = fmaf(wr, u.x, acc[r][0]);
                acc[r][1] = fmaf(wr, u.y, acc[r][1]);
                acc[r][2] = fmaf(wr, u.z, acc[r][2]);
                acc[r][3] = fmaf(wr, u.w, acc[r][3]);
            }
        }
        if (c < 7) { __syncthreads(); buf ^= 1; }
    }

    if (colf < SROW) {
        float* vo = v + (size_t)b * (W * SROW) + colf;
        #pragma unroll
        for (int r = 0; r < 8; r++) {
            float4 o4;
            o4.x = gelu_exact(acc[r][0]);
            o4.y = gelu_exact(acc[r][1]);
            o4.z = gelu_exact(acc[r][2]);
            o4.w = gelu_exact(acc[r][3]);
            *(float4*)(vo + (size_t)(wvu * 8 + r) * SROW) = o4;
        }
    }
}

// Final projection: 1024 threads = 16 waves; wave w owns h rows [8w,8w+8)
// (weights wave-uniform -> s_load); thread tile 8h x 4n (acc=32 regs, NO SPILL).
// Block covers 128h x 256n; K=64 in 8 chunks of 8 rows, LDS double-buffered.
// Per-wave partial dot with w2, LDS reduce across 16 waves.
__global__ __launch_bounds__(1024, 4) void kproj(const float* __restrict__ v,
        const float* __restrict__ w1, const float* __restrict__ b1,
        const float* __restrict__ w2, const float* __restrict__ b2,
        float* __restrict__ out) {
    __shared__ __align__(16) float U[2][8][256];     // 16 KB
    __shared__ __align__(16) float red[16][256];     // 16 KB
    int t = threadIdx.x;
    int b = blockIdx.y;
    int n0 = blockIdx.x * 256;   // 32 blocks x 256 = 8192 exact
    int lane = t & 63;
    int wvu = __builtin_amdgcn_readfirstlane(t >> 6);   // 0..15
    const float* vb = v + (size_t)b * (W * SROW);
    int colf = n0 + lane * 4;
    int h0 = wvu * 8;

    // stage chunk 0 (rows 0..7): waves 0..7, one row each
    if (wvu < 8) gld16(vb + (size_t)wvu * SROW + colf, &U[0][wvu][0]);

    float acc[8][4];
    #pragma unroll
    for (int r = 0; r < 8; r++) {
        float bs = b1[h0 + r];                      // uniform -> s_load
        acc[r][0] = acc[r][1] = acc[r][2] = acc[r][3] = bs;
    }
    __syncthreads();

    int buf = 0;
    for (int c = 0; c < 8; c++) {
        if (c < 7 && wvu < 8)
            gld16(vb + (size_t)((c + 1) * 8 + wvu) * SROW + colf, &U[buf ^ 1][wvu][0]);
        #pragma unroll
        for (int kk = 0; kk < 8; kk++) {
            int k = c * 8 + kk;
            float4 u = *(const float4*)&U[buf][kk][lane * 4];
            const float* wk = w1 + k * 128 + h0;    // uniform -> s_load
            #pragma unroll
            for (int r = 0; r < 8; r++) {
                float wr = wk[r];
                acc[r][0] = fmaf(wr, u.x, acc[r][0]);
                acc[r][1] = fmaf(wr, u.y, acc[r][1]);
                acc[r][2] = fmaf(wr, u.z, acc[r][2]);
                acc[r][3] = fmaf(wr, u.w, acc[r][3]);
            }
        }
        if (c < 7) { __syncthreads(); buf ^= 1; }
    }

    float p0 = 0.f, p1 = 0.f, p2 = 0.f, p3 = 0.f;
    #pragma unroll
    for (int r = 0; r < 8; r++) {
        float wh = w2[h0 + r];                      // uniform -> s_load
        p0 = fmaf(gelu_exact(acc[r][0]), wh, p0);
        p1 = fmaf(gelu_exact(acc[r][1]), wh, p1);
        p2 = fmaf(gelu_exact(acc[r][2]), wh, p2);
        p3 = fmaf(gelu_exact(acc[r][3]), wh, p3);
    }
    float4 p4 = {p0, p1, p2, p3};
    *(float4*)&red[wvu][lane * 4] = p4;
    __syncthreads();
    if (t < 256) {
        float s = b2[0];
        #pragma unroll
        for (int w = 0; w < 16; w++) s += red[w][t];
        out[(size_t)b * 8192 + n0 + t] = s;
    }
}

extern "C" void kernel_launch(void* const* d_in, const int* in_sizes, int n_in,
                              void* d_out, int out_size, void* d_ws, size_t ws_size,
                              hipStream_t stream) {
    const float* x  = (const float*)d_in[0];
    const float* lw = (const float*)d_in[1];
    const float* lb = (const float*)d_in[2];
    const float* kr = (const float*)d_in[3];
    const float* ki = (const float*)d_in[4];
    const float* cw = (const float*)d_in[5];
    const float* cb = (const float*)d_in[6];
    const float* w1 = (const float*)d_in[7];
    const float* b1 = (const float*)d_in[8];
    const float* w2 = (const float*)d_in[9];
    const float* b2 = (const float*)d_in[10];
    float* out = (float*)d_out;

    // workspace (floats): v 33,619,968 | cosT/sinT 131,328 ea | onesz 24,624 |
    // F/Pm 131,072 ea | Wf 393,216  => ~138.3 MB
    float* ws = (float*)d_ws;
    size_t vsz = (size_t)NB * W * SROW;
    float* v     = ws;
    float* cosT  = v + vsz;
    float* sinT  = cosT + (size_t)16 * SROW;
    float* onesz = sinT + (size_t)16 * SROW;
    float* F     = onesz + (size_t)3 * SROW;
    float* Pm    = F + (size_t)NB * W * M * 2;
    float* Wf    = Pm + (size_t)NB * W * M * 2;

    ktable<<<dim3(33, 18), 256, 0, stream>>>(cosT, sinT, onesz);
    klift<<<dim3(33, NB), 256, 0, stream>>>(x, lw, lb, v);

    for (int l = 0; l < NL; l++) {
        kdft<<<NB * W / 4, 256, 0, stream>>>(v, cosT, sinT, F);
        kmix<<<dim3(NB, 4), 256, 0, stream>>>(F, kr, ki, Pm, l);
        kprep<<<NB, 256, 0, stream>>>(Pm, cw, cb, Wf, l);
        kconv<<<dim3(33, NB), 512, 0, stream>>>(v, Wf, cosT, sinT, onesz);
    }
    kproj<<<dim3(32, NB), 1024, 0, stream>>>(v, w1, b1, w2, b2, out);
}